// Round 1
// baseline (3020.060 us; speedup 1.0000x reference)
//
#include <hip/hip_runtime.h>
#include <cstdint>
#include <cstddef>

#define B   32
#define N   4096
#define NP  512
#define NS  16
#define C   256
#define CIN 259
#define HID 128
#define SB  (NP*NS)      // 8192 columns per batch
#define S   (B*SB)       // 262144 total columns
#define EPSF 1e-5f

// ---------------- prep: transpose weights (k-major), zero stats ----------------
__global__ void prep_kernel(const float* __restrict__ w1, const float* __restrict__ w2,
                            const float* __restrict__ w3, float* __restrict__ w1t,
                            float* __restrict__ w2t, float* __restrict__ w3t,
                            float* __restrict__ stats) {
    int i = blockIdx.x * blockDim.x + threadIdx.x;
    if (i < CIN * HID) { int k = i / HID, o = i % HID; w1t[i] = w1[o * CIN + k]; }
    if (i < HID * HID) { int k = i / HID, o = i % HID; w2t[i] = w2[o * HID + k]; w3t[i] = w3[o * HID + k]; }
    if (i < 3 * 512) stats[i] = 0.f;
}

// ---------------- FPS (matches jnp argmax semantics exactly) ----------------
__global__ __launch_bounds__(512) void fps_kernel(const float* __restrict__ seed,
        const float* __restrict__ xyz, int* __restrict__ inds,
        float* __restrict__ out_newxyz, float* __restrict__ out_inds_f) {
    __shared__ float sx[N], sy[N], sz[N];
    __shared__ float rbv[8]; __shared__ int rbi[8]; __shared__ int s_last;
    int b = blockIdx.x, t = threadIdx.x;
    const float* sp = seed + (size_t)b * N * 3;
    float dloc[8];
    #pragma unroll
    for (int u = 0; u < 8; u++) {
        int i = t + 512 * u;
        sx[i] = sp[i * 3 + 0]; sy[i] = sp[i * 3 + 1]; sz[i] = sp[i * 3 + 2];
        dloc[u] = 1e10f;
    }
    int* binds = inds + b * NP;
    if (t == 0) { s_last = 0; binds[0] = 0; }
    __syncthreads();
    for (int k = 1; k < NP; k++) {
        int last = s_last;
        float lx = sx[last], ly = sy[last], lz = sz[last];
        float bv = -1.f; int bi = 0x7fffffff;
        #pragma unroll
        for (int u = 0; u < 8; u++) {
            int i = t + 512 * u;
            float dx = __fsub_rn(sx[i], lx);
            float dy = __fsub_rn(sy[i], ly);
            float dz = __fsub_rn(sz[i], lz);
            float d  = __fadd_rn(__fadd_rn(__fmul_rn(dx, dx), __fmul_rn(dy, dy)), __fmul_rn(dz, dz));
            float dm = fminf(dloc[u], d);
            dloc[u] = dm;
            if (dm > bv || (dm == bv && i < bi)) { bv = dm; bi = i; }
        }
        #pragma unroll
        for (int off = 32; off > 0; off >>= 1) {
            float ov = __shfl_down(bv, off); int oi = __shfl_down(bi, off);
            if (ov > bv || (ov == bv && oi < bi)) { bv = ov; bi = oi; }
        }
        if ((t & 63) == 0) { rbv[t >> 6] = bv; rbi[t >> 6] = bi; }
        __syncthreads();
        if (t == 0) {
            bv = rbv[0]; bi = rbi[0];
            #pragma unroll
            for (int j = 1; j < 8; j++)
                if (rbv[j] > bv || (rbv[j] == bv && rbi[j] < bi)) { bv = rbv[j]; bi = rbi[j]; }
            s_last = bi; binds[k] = bi;
        }
        __syncthreads();
    }
    for (int p = t; p < NP; p += 512) {
        int j = binds[p];
        const float* xb = xyz + ((size_t)b * N + j) * 3;
        float* ob = out_newxyz + ((size_t)b * NP + p) * 3;
        ob[0] = xb[0]; ob[1] = xb[1]; ob[2] = xb[2];
        out_inds_f[b * NP + p] = (float)j;   // indices stored as f32 in flat output
    }
}

// ---------------- ball query: first NS indices with d2 < r^2, pad with first ----------------
__global__ __launch_bounds__(128) void ballquery_kernel(const float* __restrict__ xyz,
        const float* __restrict__ newxyz, int* __restrict__ idx) {
    __shared__ float sx[N], sy[N], sz[N];
    int b  = blockIdx.x >> 2;
    int q0 = (blockIdx.x & 3) * 128;
    int t  = threadIdx.x;
    const float* xb = xyz + (size_t)b * N * 3;
    for (int i = t; i < N; i += 128) { sx[i] = xb[i * 3]; sy[i] = xb[i * 3 + 1]; sz[i] = xb[i * 3 + 2]; }
    __syncthreads();
    int q = q0 + t;
    const float* nq = newxyz + ((size_t)b * NP + q) * 3;
    float qx = nq[0], qy = nq[1], qz = nq[2];
    int* out = idx + ((size_t)b * NP + q) * NS;
    int cnt = 0, first = 0;
    for (int j = 0; j < N; j++) {
        float dx = __fsub_rn(sx[j], qx);
        float dy = __fsub_rn(sy[j], qy);
        float dz = __fsub_rn(sz[j], qz);
        float d2 = __fadd_rn(__fadd_rn(__fmul_rn(dx, dx), __fmul_rn(dy, dy)), __fmul_rn(dz, dz));
        if (d2 < 0.09f) {
            if (cnt == 0) first = j;
            out[cnt] = j;
            cnt++;
            if (cnt == NS) break;
        }
    }
    for (int c = cnt; c < NS; c++) out[c] = first;
}

// ---------------- GEMM1: Y1 = W1 * [xyz_norm ; gathered feat], + per-channel stats ----------------
__global__ __launch_bounds__(256) void gemm1_kernel(const float* __restrict__ w1t,
        const float* __restrict__ xyz, const float* __restrict__ feat,
        const float* __restrict__ newxyz, const int* __restrict__ idx,
        float* __restrict__ yout, float* __restrict__ stats) {
    __shared__ float Ws[16 * 128];
    __shared__ float Xs[16 * 132];
    __shared__ float xn[3][128];
    __shared__ int   jl[128];
    __shared__ float bsum[128], bsq[128];
    int t  = threadIdx.x;
    int s0 = blockIdx.x * 128;
    int b  = s0 / SB;
    if (t < 128) {
        int pn = s0 - b * SB + t;
        int p = pn >> 4, n = pn & 15;
        int j = idx[((size_t)b * NP + p) * NS + n];
        jl[t] = j;
        const float* xb = xyz + ((size_t)b * N + j) * 3;
        const float* nq = newxyz + ((size_t)b * NP + p) * 3;
        xn[0][t] = (xb[0] - nq[0]) / 0.3f;
        xn[1][t] = (xb[1] - nq[1]) / 0.3f;
        xn[2][t] = (xb[2] - nq[2]) / 0.3f;
        bsum[t] = 0.f; bsq[t] = 0.f;
    }
    __syncthreads();
    const float* fb = feat + (size_t)b * C * N;
    float acc[8][8] = {};
    int tx = t & 15, ty = t >> 4;
    for (int kt = 0; kt < CIN; kt += 16) {
        #pragma unroll
        for (int i = 0; i < 8; i++) {
            int lin = t + 256 * i;
            int o = lin & 127, kk = lin >> 7;
            int k = kt + kk;
            Ws[kk * 128 + o] = (k < CIN) ? w1t[k * HID + o] : 0.f;
        }
        #pragma unroll
        for (int i = 0; i < 8; i++) {
            int lin = t + 256 * i;
            int sc = lin & 127, kk = lin >> 7;
            int k = kt + kk;
            float v = 0.f;
            if (k < 3) v = xn[k][sc];
            else if (k < CIN) v = fb[(size_t)(k - 3) * N + jl[sc]];
            Xs[kk * 132 + sc] = v;
        }
        __syncthreads();
        #pragma unroll
        for (int kk = 0; kk < 16; kk++) {
            float wv[8], xv[8];
            #pragma unroll
            for (int r = 0; r < 8; r++) wv[r] = Ws[kk * 128 + ty * 8 + r];
            #pragma unroll
            for (int c = 0; c < 8; c++) xv[c] = Xs[kk * 132 + tx * 8 + c];
            #pragma unroll
            for (int r = 0; r < 8; r++)
                #pragma unroll
                for (int c = 0; c < 8; c++)
                    acc[r][c] = fmaf(wv[r], xv[c], acc[r][c]);
        }
        __syncthreads();
    }
    #pragma unroll
    for (int r = 0; r < 8; r++) {
        int o = ty * 8 + r;
        float ls = 0.f, lq = 0.f;
        #pragma unroll
        for (int c = 0; c < 8; c++) {
            float v = acc[r][c];
            ls += v; lq = fmaf(v, v, lq);
            yout[(size_t)o * S + s0 + tx * 8 + c] = v;
        }
        atomicAdd(&bsum[o], ls);
        atomicAdd(&bsq[o], lq);
    }
    __syncthreads();
    if (t < 128) {
        atomicAdd(&stats[t], bsum[t]);
        atomicAdd(&stats[128 + t], bsq[t]);
    }
}

// ---------------- GEMM2/3: X = relu(affine(Yprev)), Y = W*X, + stats ----------------
__global__ __launch_bounds__(256) void gemm_bn_kernel(const float* __restrict__ wt,
        const float* __restrict__ yprev, const float* __restrict__ statsPrev,
        float* __restrict__ yout, float* __restrict__ statsOut) {
    __shared__ float Ws[16 * 128];
    __shared__ float Xs[16 * 132];
    __shared__ float ssc[128], ssh[128];
    __shared__ float bsum[128], bsq[128];
    int t  = threadIdx.x;
    int s0 = blockIdx.x * 128;
    if (t < 128) {
        ssc[t] = statsPrev[256 + t];
        ssh[t] = statsPrev[384 + t];
        bsum[t] = 0.f; bsq[t] = 0.f;
    }
    __syncthreads();
    float acc[8][8] = {};
    int tx = t & 15, ty = t >> 4;
    for (int kt = 0; kt < HID; kt += 16) {
        #pragma unroll
        for (int i = 0; i < 8; i++) {
            int lin = t + 256 * i;
            int o = lin & 127, kk = lin >> 7;
            Ws[kk * 128 + o] = wt[(kt + kk) * HID + o];
        }
        #pragma unroll
        for (int i = 0; i < 8; i++) {
            int lin = t + 256 * i;
            int sc = lin & 127, kk = lin >> 7;
            int k = kt + kk;
            float v = yprev[(size_t)k * S + s0 + sc];
            Xs[kk * 132 + sc] = fmaxf(0.f, fmaf(v, ssc[k], ssh[k]));
        }
        __syncthreads();
        #pragma unroll
        for (int kk = 0; kk < 16; kk++) {
            float wv[8], xv[8];
            #pragma unroll
            for (int r = 0; r < 8; r++) wv[r] = Ws[kk * 128 + ty * 8 + r];
            #pragma unroll
            for (int c = 0; c < 8; c++) xv[c] = Xs[kk * 132 + tx * 8 + c];
            #pragma unroll
            for (int r = 0; r < 8; r++)
                #pragma unroll
                for (int c = 0; c < 8; c++)
                    acc[r][c] = fmaf(wv[r], xv[c], acc[r][c]);
        }
        __syncthreads();
    }
    #pragma unroll
    for (int r = 0; r < 8; r++) {
        int o = ty * 8 + r;
        float ls = 0.f, lq = 0.f;
        #pragma unroll
        for (int c = 0; c < 8; c++) {
            float v = acc[r][c];
            ls += v; lq = fmaf(v, v, lq);
            yout[(size_t)o * S + s0 + tx * 8 + c] = v;
        }
        atomicAdd(&bsum[o], ls);
        atomicAdd(&bsq[o], lq);
    }
    __syncthreads();
    if (t < 128) {
        atomicAdd(&statsOut[t], bsum[t]);
        atomicAdd(&statsOut[128 + t], bsq[t]);
    }
}

// ---------------- BN params: scale/shift from batch stats ----------------
__global__ void bnparam_kernel(float* __restrict__ stats, const float* __restrict__ g,
                               const float* __restrict__ be) {
    int o = threadIdx.x;
    float mean = stats[o] * (1.f / (float)S);          // S = 2^18 -> exact
    float var  = stats[128 + o] * (1.f / (float)S) - mean * mean;
    float sc = g[o] / sqrtf(var + EPSF);
    stats[256 + o] = sc;
    stats[384 + o] = be[o] - mean * sc;
}

// ---------------- final: affine+relu+max over NS ----------------
__global__ __launch_bounds__(256) void maxpool_kernel(const float* __restrict__ y3,
        const float* __restrict__ stats3, float* __restrict__ out1) {
    int i = blockIdx.x * 256 + threadIdx.x;
    if (i >= B * HID * NP) return;
    int p = i % NP;
    int o = (i / NP) % HID;
    int b = i / (NP * HID);
    float sc = stats3[256 + o], sh = stats3[384 + o];
    size_t base = (size_t)o * S + (size_t)(b * NP + p) * NS;
    float m = 0.f;   // relu floor
    #pragma unroll
    for (int n = 0; n < NS; n++) {
        float v = fmaf(y3[base + n], sc, sh);
        m = fmaxf(m, v);
    }
    out1[i] = m;
}

extern "C" void kernel_launch(void* const* d_in, const int* in_sizes, int n_in,
                              void* d_out, int out_size, void* d_ws, size_t ws_size,
                              hipStream_t stream) {
    const float* xyz  = (const float*)d_in[0];
    const float* feat = (const float*)d_in[1];
    const float* seed = (const float*)d_in[2];
    const float* w1 = (const float*)d_in[3];
    const float* g1 = (const float*)d_in[4];
    const float* be1 = (const float*)d_in[5];
    const float* w2 = (const float*)d_in[6];
    const float* g2 = (const float*)d_in[7];
    const float* be2 = (const float*)d_in[8];
    const float* w3 = (const float*)d_in[9];
    const float* g3 = (const float*)d_in[10];
    const float* be3 = (const float*)d_in[11];

    float* out_newxyz = (float*)d_out;                 // (B,NP,3)
    float* out_feat   = out_newxyz + B * NP * 3;       // (B,HID,NP)
    float* out_inds   = out_feat + B * HID * NP;       // (B,NP) as float

    float* stats = (float*)d_ws;                       // 3 layers x [sum|sq|scale|shift] x 128
    int*   inds  = (int*)(stats + 3 * 512);            // B*NP
    int*   idx   = inds + B * NP;                      // B*NP*NS
    float* w1t   = (float*)(idx + (size_t)B * NP * NS);
    float* w2t   = w1t + CIN * HID;
    float* w3t   = w2t + HID * HID;
    float* y1    = w3t + HID * HID;
    float* y2    = y1 + (size_t)HID * S;
    float* y3    = y1;                                 // alias: y1 dead before gemm3 writes

    size_t need = ((size_t)(3 * 512 + B * NP + (size_t)B * NP * NS + CIN * HID + 2 * HID * HID)
                   + 2 * (size_t)HID * S) * 4;

    if (ws_size < (size_t)(3 * 512 + B * NP) * 4) return;   // can't even do FPS

    fps_kernel<<<B, 512, 0, stream>>>(seed, xyz, inds, out_newxyz, out_inds);

    if (ws_size < need) return;   // diagnostic: outputs 0 and 2 valid, 1 poison

    prep_kernel<<<(CIN * HID + 255) / 256, 256, 0, stream>>>(w1, w2, w3, w1t, w2t, w3t, stats);
    ballquery_kernel<<<B * 4, 128, 0, stream>>>(xyz, out_newxyz, idx);
    gemm1_kernel<<<S / 128, 256, 0, stream>>>(w1t, xyz, feat, out_newxyz, idx, y1, stats);
    bnparam_kernel<<<1, HID, 0, stream>>>(stats, g1, be1);
    gemm_bn_kernel<<<S / 128, 256, 0, stream>>>(w2t, y1, stats, y2, stats + 512);
    bnparam_kernel<<<1, HID, 0, stream>>>(stats + 512, g2, be2);
    gemm_bn_kernel<<<S / 128, 256, 0, stream>>>(w3t, y2, stats + 512, y3, stats + 1024);
    bnparam_kernel<<<1, HID, 0, stream>>>(stats + 1024, g3, be3);
    maxpool_kernel<<<(B * HID * NP + 255) / 256, 256, 0, stream>>>(y3, stats + 1024, out_feat);
}

// Round 4
// 1731.438 us; speedup vs baseline: 1.7442x; 1.7442x over previous
//
#include <hip/hip_runtime.h>
#include <cstdint>
#include <cstddef>

#define B   32
#define N   4096
#define NP  512
#define NS  16
#define C   256
#define CIN 259
#define HID 128
#define SB  (NP*NS)      // 8192 columns per batch
#define S   (B*SB)       // 262144 total columns
#define EPSF 1e-5f

// ---------------- prep: w1 feat-part k-major, w2/w3 k-major, zero stats ----------------
__global__ void prep_kernel(const float* __restrict__ w1, const float* __restrict__ w2,
                            const float* __restrict__ w3, float* __restrict__ w1ft,
                            float* __restrict__ w2t, float* __restrict__ w3t,
                            float* __restrict__ stats) {
    int i = blockIdx.x * blockDim.x + threadIdx.x;
    if (i < 256 * HID) { int k = i >> 7, o = i & 127; w1ft[i] = w1[o * CIN + 3 + k]; }
    if (i < HID * HID) { int k = i >> 7, o = i & 127; w2t[i] = w2[o * HID + k]; w3t[i] = w3[o * HID + k]; }
    if (i < 3 * 512) stats[i] = 0.f;
}

// ---------------- transpose feat (B,C,N) -> featT (B,N,256) ----------------
__global__ __launch_bounds__(256) void transpose_kernel(const float* __restrict__ feat,
                                                        float* __restrict__ featT) {
    __shared__ float ls[32][129];
    int blk = blockIdx.x;
    int b   = blk >> 8;          // 256 tiles per batch
    int rem = blk & 255;
    int ct = rem >> 5, jt = rem & 31;
    int c0 = ct * 32, j0 = jt * 128;
    const float* src = feat + (size_t)b * C * N;
    int t = threadIdx.x;
    #pragma unroll
    for (int i = 0; i < 16; i++) {
        int lin = t + 256 * i;
        int jj = lin & 127, cc = lin >> 7;
        ls[cc][jj] = src[(size_t)(c0 + cc) * N + j0 + jj];
    }
    __syncthreads();
    float4* dst = (float4*)featT;
    #pragma unroll
    for (int i = 0; i < 4; i++) {
        int lin = t + 256 * i;
        int cc4 = lin & 7, jj = lin >> 3;
        float4 v = make_float4(ls[cc4 * 4 + 0][jj], ls[cc4 * 4 + 1][jj],
                               ls[cc4 * 4 + 2][jj], ls[cc4 * 4 + 3][jj]);
        dst[((size_t)b * N + j0 + jj) * 64 + ct * 8 + cc4] = v;
    }
}

// ---------------- FPS (coords in registers; selection arithmetic identical to r1) ----------------
__global__ __launch_bounds__(512) void fps_kernel(const float* __restrict__ seed,
        const float* __restrict__ xyz, int* __restrict__ inds,
        float* __restrict__ out_newxyz, float* __restrict__ out_inds_f) {
    __shared__ float sx[N], sy[N], sz[N];
    __shared__ float rbv[8]; __shared__ int rbi[8]; __shared__ int s_last;
    int b = blockIdx.x, t = threadIdx.x;
    const float* sp = seed + (size_t)b * N * 3;
    float px[8], py[8], pz[8], dloc[8];
    #pragma unroll
    for (int u = 0; u < 8; u++) {
        int i = t + 512 * u;
        float x = sp[i * 3 + 0], y = sp[i * 3 + 1], z = sp[i * 3 + 2];
        sx[i] = x; sy[i] = y; sz[i] = z;
        px[u] = x; py[u] = y; pz[u] = z;
        dloc[u] = 1e10f;
    }
    int* binds = inds + b * NP;
    if (t == 0) { s_last = 0; binds[0] = 0; }
    __syncthreads();
    for (int k = 1; k < NP; k++) {
        int last = s_last;
        float lx = sx[last], ly = sy[last], lz = sz[last];
        float bv = -1.f; int bi = 0x7fffffff;
        #pragma unroll
        for (int u = 0; u < 8; u++) {
            int i = t + 512 * u;
            float dx = __fsub_rn(px[u], lx);
            float dy = __fsub_rn(py[u], ly);
            float dz = __fsub_rn(pz[u], lz);
            float d  = __fadd_rn(__fadd_rn(__fmul_rn(dx, dx), __fmul_rn(dy, dy)), __fmul_rn(dz, dz));
            float dm = fminf(dloc[u], d);
            dloc[u] = dm;
            if (dm > bv || (dm == bv && i < bi)) { bv = dm; bi = i; }
        }
        #pragma unroll
        for (int off = 32; off > 0; off >>= 1) {
            float ov = __shfl_down(bv, off); int oi = __shfl_down(bi, off);
            if (ov > bv || (ov == bv && oi < bi)) { bv = ov; bi = oi; }
        }
        if ((t & 63) == 0) { rbv[t >> 6] = bv; rbi[t >> 6] = bi; }
        __syncthreads();
        if (t == 0) {
            bv = rbv[0]; bi = rbi[0];
            #pragma unroll
            for (int j = 1; j < 8; j++)
                if (rbv[j] > bv || (rbv[j] == bv && rbi[j] < bi)) { bv = rbv[j]; bi = rbi[j]; }
            s_last = bi; binds[k] = bi;
        }
        __syncthreads();
    }
    for (int p = t; p < NP; p += 512) {
        int j = binds[p];
        const float* xb = xyz + ((size_t)b * N + j) * 3;
        float* ob = out_newxyz + ((size_t)b * NP + p) * 3;
        ob[0] = xb[0]; ob[1] = xb[1]; ob[2] = xb[2];
        out_inds_f[b * NP + p] = (float)j;
    }
}

// ---------------- ball query: wave-parallel ballot scan, first NS by index ----------------
__global__ __launch_bounds__(256) void ballquery_kernel(const float* __restrict__ xyz,
        const float* __restrict__ newxyz, int* __restrict__ idx) {
    __shared__ float sx[N], sy[N], sz[N];
    int blk = blockIdx.x;            // 1024 blocks: 32 per batch, 16 queries each
    int b   = blk >> 5;
    int q00 = (blk & 31) * 16;
    int t = threadIdx.x, lane = t & 63, w = t >> 6;
    const float* xb = xyz + (size_t)b * N * 3;
    for (int i = t; i < N; i += 256) { sx[i] = xb[i * 3]; sy[i] = xb[i * 3 + 1]; sz[i] = xb[i * 3 + 2]; }
    __syncthreads();
    for (int qi = 0; qi < 4; qi++) {
        int q = q00 + w * 4 + qi;
        const float* nq = newxyz + ((size_t)(b * NP + q)) * 3;
        float qx = nq[0], qy = nq[1], qz = nq[2];
        int* out = idx + ((size_t)(b * NP + q)) * NS;
        int cnt = 0, first = -1;
        for (int it = 0; it < 64; it++) {
            int j = it * 64 + lane;
            float dx = __fsub_rn(sx[j], qx);
            float dy = __fsub_rn(sy[j], qy);
            float dz = __fsub_rn(sz[j], qz);
            float d2 = __fadd_rn(__fadd_rn(__fmul_rn(dx, dx), __fmul_rn(dy, dy)), __fmul_rn(dz, dz));
            bool inb = d2 < 0.09f;
            unsigned long long m = __ballot(inb);
            if (m) {
                if (first < 0) first = it * 64 + __builtin_ctzll(m);
                if (inb) {
                    int r = cnt + __popcll(m & ((1ull << lane) - 1ull));
                    if (r < NS) out[r] = j;
                }
                cnt += __popcll(m);
                if (cnt >= NS) break;
            }
        }
        if (cnt < NS && lane >= cnt && lane < NS) out[lane] = first;
    }
}

// ---------------- GEMM1: Y1 = W1feat * gathered featT rows (+xyz in epilogue), + stats ----------------
__global__ __launch_bounds__(256) void gemm1_kernel(const float* __restrict__ w1ft,
        const float* __restrict__ w1raw, const float* __restrict__ featT,
        const float* __restrict__ newxyz, const float* __restrict__ xyz,
        const int* __restrict__ idx, float* __restrict__ yout, float* __restrict__ stats) {
    __shared__ float Ws[32 * 128];
    __shared__ float Xs[32 * 132];
    __shared__ float xn0[128], xn1[128], xn2[128];
    __shared__ int   jl[128];
    __shared__ float bsum[128], bsq[128];
    int t  = threadIdx.x;
    int s0 = blockIdx.x * 128;
    int b  = s0 >> 13;
    if (t < 128) {
        int pn = (s0 & (SB - 1)) + t;
        int p = pn >> 4, n = pn & 15;
        int j = idx[((size_t)(b * NP + p)) * NS + n];
        jl[t] = j;
        const float* xb = xyz + ((size_t)(b * N + j)) * 3;
        const float* nq = newxyz + ((size_t)(b * NP + p)) * 3;
        xn0[t] = (xb[0] - nq[0]) / 0.3f;
        xn1[t] = (xb[1] - nq[1]) / 0.3f;
        xn2[t] = (xb[2] - nq[2]) / 0.3f;
        bsum[t] = 0.f; bsq[t] = 0.f;
    }
    __syncthreads();
    const float4* fT = (const float4*)featT + (size_t)b * N * 64;
    const float4* W4 = (const float4*)w1ft;
    float acc[8][8] = {};
    int tx = t & 15, ty = t >> 4;
    int colA = t >> 3, q = t & 7;
    long rb0 = (long)jl[colA] * 64,      rb1 = (long)jl[colA + 32] * 64;
    long rb2 = (long)jl[colA + 64] * 64, rb3 = (long)jl[colA + 96] * 64;
    for (int kt = 0; kt < 256; kt += 32) {
        int kq = kt >> 2;
        #pragma unroll
        for (int i = 0; i < 4; i++) {
            int lin = t + 256 * i;
            int kk = lin >> 5, of4 = lin & 31;
            *(float4*)&Ws[kk * 128 + of4 * 4] = W4[(size_t)(kt + kk) * 32 + of4];
        }
        float4 x0 = fT[rb0 + kq + q];
        float4 x1 = fT[rb1 + kq + q];
        float4 x2 = fT[rb2 + kq + q];
        float4 x3 = fT[rb3 + kq + q];
        int kr = q * 4;
        Xs[(kr+0)*132 + colA]    = x0.x; Xs[(kr+1)*132 + colA]    = x0.y;
        Xs[(kr+2)*132 + colA]    = x0.z; Xs[(kr+3)*132 + colA]    = x0.w;
        Xs[(kr+0)*132 + colA+32] = x1.x; Xs[(kr+1)*132 + colA+32] = x1.y;
        Xs[(kr+2)*132 + colA+32] = x1.z; Xs[(kr+3)*132 + colA+32] = x1.w;
        Xs[(kr+0)*132 + colA+64] = x2.x; Xs[(kr+1)*132 + colA+64] = x2.y;
        Xs[(kr+2)*132 + colA+64] = x2.z; Xs[(kr+3)*132 + colA+64] = x2.w;
        Xs[(kr+0)*132 + colA+96] = x3.x; Xs[(kr+1)*132 + colA+96] = x3.y;
        Xs[(kr+2)*132 + colA+96] = x3.z; Xs[(kr+3)*132 + colA+96] = x3.w;
        __syncthreads();
        #pragma unroll 4
        for (int kk = 0; kk < 32; kk++) {
            float wv[8], xv[8];
            *(float4*)&wv[0] = *(const float4*)&Ws[kk * 128 + ty * 8];
            *(float4*)&wv[4] = *(const float4*)&Ws[kk * 128 + ty * 8 + 4];
            *(float4*)&xv[0] = *(const float4*)&Xs[kk * 132 + tx * 8];
            *(float4*)&xv[4] = *(const float4*)&Xs[kk * 132 + tx * 8 + 4];
            #pragma unroll
            for (int r = 0; r < 8; r++)
                #pragma unroll
                for (int c = 0; c < 8; c++)
                    acc[r][c] = fmaf(wv[r], xv[c], acc[r][c]);
        }
        __syncthreads();
    }
    float xnc0[8], xnc1[8], xnc2[8];
    #pragma unroll
    for (int c = 0; c < 8; c++) {
        int col = tx * 8 + c;
        xnc0[c] = xn0[col]; xnc1[c] = xn1[col]; xnc2[c] = xn2[col];
    }
    #pragma unroll
    for (int r = 0; r < 8; r++) {
        int o = ty * 8 + r;
        const float* wr = w1raw + (size_t)o * CIN;
        float wa = wr[0], wb = wr[1], wc = wr[2];
        float ls = 0.f, lq = 0.f;
        #pragma unroll
        for (int c = 0; c < 8; c++) {
            float v = acc[r][c] + wa * xnc0[c] + wb * xnc1[c] + wc * xnc2[c];
            ls += v; lq = fmaf(v, v, lq);
            yout[(size_t)o * S + s0 + tx * 8 + c] = v;
        }
        atomicAdd(&bsum[o], ls);
        atomicAdd(&bsq[o], lq);
    }
    __syncthreads();
    if (t < 128) {
        atomicAdd(&stats[t], bsum[t]);
        atomicAdd(&stats[128 + t], bsq[t]);
    }
}

// ---------------- GEMM2/3: X = relu(affine(Yprev)), Y = W*X, + stats ----------------
__global__ __launch_bounds__(256) void gemm_bn_kernel(const float* __restrict__ wt,
        const float* __restrict__ yprev, const float* __restrict__ statsPrev,
        float* __restrict__ yout, float* __restrict__ statsOut) {
    __shared__ float Ws[32 * 128];
    __shared__ float Xs[32 * 132];
    __shared__ float ssc[128], ssh[128];
    __shared__ float bsum[128], bsq[128];
    int t  = threadIdx.x;
    int s0 = blockIdx.x * 128;
    if (t < 128) {
        ssc[t] = statsPrev[256 + t];
        ssh[t] = statsPrev[384 + t];
        bsum[t] = 0.f; bsq[t] = 0.f;
    }
    __syncthreads();
    const float4* W4 = (const float4*)wt;
    float acc[8][8] = {};
    int tx = t & 15, ty = t >> 4;
    for (int kt = 0; kt < HID; kt += 32) {
        #pragma unroll
        for (int i = 0; i < 4; i++) {
            int lin = t + 256 * i;
            int kk = lin >> 5, of4 = lin & 31;
            *(float4*)&Ws[kk * 128 + of4 * 4] = W4[(size_t)(kt + kk) * 32 + of4];
        }
        #pragma unroll
        for (int i = 0; i < 4; i++) {
            int lin = t + 256 * i;
            int kk = lin >> 5, sc4 = lin & 31;
            int k = kt + kk;
            float4 v = *(const float4*)&yprev[(size_t)k * S + s0 + sc4 * 4];
            float sck = ssc[k], shk = ssh[k];
            v.x = fmaxf(0.f, fmaf(v.x, sck, shk));
            v.y = fmaxf(0.f, fmaf(v.y, sck, shk));
            v.z = fmaxf(0.f, fmaf(v.z, sck, shk));
            v.w = fmaxf(0.f, fmaf(v.w, sck, shk));
            *(float4*)&Xs[kk * 132 + sc4 * 4] = v;
        }
        __syncthreads();
        #pragma unroll 4
        for (int kk = 0; kk < 32; kk++) {
            float wv[8], xv[8];
            *(float4*)&wv[0] = *(const float4*)&Ws[kk * 128 + ty * 8];
            *(float4*)&wv[4] = *(const float4*)&Ws[kk * 128 + ty * 8 + 4];
            *(float4*)&xv[0] = *(const float4*)&Xs[kk * 132 + tx * 8];
            *(float4*)&xv[4] = *(const float4*)&Xs[kk * 132 + tx * 8 + 4];
            #pragma unroll
            for (int r = 0; r < 8; r++)
                #pragma unroll
                for (int c = 0; c < 8; c++)
                    acc[r][c] = fmaf(wv[r], xv[c], acc[r][c]);
        }
        __syncthreads();
    }
    #pragma unroll
    for (int r = 0; r < 8; r++) {
        int o = ty * 8 + r;
        float ls = 0.f, lq = 0.f;
        #pragma unroll
        for (int c = 0; c < 8; c++) {
            float v = acc[r][c];
            ls += v; lq = fmaf(v, v, lq);
            yout[(size_t)o * S + s0 + tx * 8 + c] = v;
        }
        atomicAdd(&bsum[o], ls);
        atomicAdd(&bsq[o], lq);
    }
    __syncthreads();
    if (t < 128) {
        atomicAdd(&statsOut[t], bsum[t]);
        atomicAdd(&statsOut[128 + t], bsq[t]);
    }
}

// ---------------- BN params ----------------
__global__ void bnparam_kernel(float* __restrict__ stats, const float* __restrict__ g,
                               const float* __restrict__ be) {
    int o = threadIdx.x;
    float mean = stats[o] * (1.f / (float)S);
    float var  = stats[128 + o] * (1.f / (float)S) - mean * mean;
    float sc = g[o] / sqrtf(var + EPSF);
    stats[256 + o] = sc;
    stats[384 + o] = be[o] - mean * sc;
}

// ---------------- final: affine+relu+max over NS ----------------
__global__ __launch_bounds__(256) void maxpool_kernel(const float* __restrict__ y3,
        const float* __restrict__ stats3, float* __restrict__ out1) {
    int i = blockIdx.x * 256 + threadIdx.x;
    if (i >= B * HID * NP) return;
    int p = i % NP;
    int o = (i / NP) % HID;
    int b = i / (NP * HID);
    float sc = stats3[256 + o], sh = stats3[384 + o];
    const float4* y4 = (const float4*)(y3 + (size_t)o * S + (size_t)(b * NP + p) * NS);
    float m = 0.f;
    #pragma unroll
    for (int n4 = 0; n4 < 4; n4++) {
        float4 v = y4[n4];
        m = fmaxf(m, fmaf(v.x, sc, sh));
        m = fmaxf(m, fmaf(v.y, sc, sh));
        m = fmaxf(m, fmaf(v.z, sc, sh));
        m = fmaxf(m, fmaf(v.w, sc, sh));
    }
    out1[i] = m;
}

extern "C" void kernel_launch(void* const* d_in, const int* in_sizes, int n_in,
                              void* d_out, int out_size, void* d_ws, size_t ws_size,
                              hipStream_t stream) {
    const float* xyz  = (const float*)d_in[0];
    const float* feat = (const float*)d_in[1];
    const float* seed = (const float*)d_in[2];
    const float* w1 = (const float*)d_in[3];
    const float* g1 = (const float*)d_in[4];
    const float* be1 = (const float*)d_in[5];
    const float* w2 = (const float*)d_in[6];
    const float* g2 = (const float*)d_in[7];
    const float* be2 = (const float*)d_in[8];
    const float* w3 = (const float*)d_in[9];
    const float* g3 = (const float*)d_in[10];
    const float* be3 = (const float*)d_in[11];

    float* out_newxyz = (float*)d_out;                 // (B,NP,3)
    float* out_feat   = out_newxyz + B * NP * 3;       // (B,HID,NP)
    float* out_inds   = out_feat + B * HID * NP;       // (B,NP) as float

    float* stats = (float*)d_ws;                       // 3 x [sum|sq|scale|shift] x 128
    int*   inds  = (int*)(stats + 3 * 512);            // B*NP
    int*   idx   = inds + B * NP;                      // B*NP*NS
    float* w1ft  = (float*)(idx + (size_t)B * NP * NS);
    float* w2t   = w1ft + 256 * HID;
    float* w3t   = w2t + HID * HID;
    float* featT = w3t + HID * HID;                    // B*N*256
    float* y1    = featT + (size_t)B * N * 256;        // HID*S
    float* y2    = featT;                              // alias: featT dead after gemm1
    float* y3    = y1;                                 // alias: y1 dead after gemm2

    size_t need = ((size_t)(3 * 512 + B * NP + (size_t)B * NP * NS
                   + 256 * HID + 2 * HID * HID)
                   + (size_t)B * N * 256 + (size_t)HID * S) * 4;

    if (ws_size < (size_t)(3 * 512 + B * NP) * 4) return;

    fps_kernel<<<B, 512, 0, stream>>>(seed, xyz, inds, out_newxyz, out_inds);

    if (ws_size < need) return;

    prep_kernel<<<(256 * HID + 255) / 256, 256, 0, stream>>>(w1, w2, w3, w1ft, w2t, w3t, stats);
    transpose_kernel<<<B * 256, 256, 0, stream>>>(feat, featT);
    ballquery_kernel<<<B * 32, 256, 0, stream>>>(xyz, out_newxyz, idx);
    gemm1_kernel<<<S / 128, 256, 0, stream>>>(w1ft, w1, featT, out_newxyz, xyz, idx, y1, stats);
    bnparam_kernel<<<1, HID, 0, stream>>>(stats, g1, be1);
    gemm_bn_kernel<<<S / 128, 256, 0, stream>>>(w2t, y1, stats, y2, stats + 512);
    bnparam_kernel<<<1, HID, 0, stream>>>(stats + 512, g2, be2);
    gemm_bn_kernel<<<S / 128, 256, 0, stream>>>(w3t, y2, stats + 512, y3, stats + 1024);
    bnparam_kernel<<<1, HID, 0, stream>>>(stats + 1024, g3, be3);
    maxpool_kernel<<<(B * HID * NP + 255) / 256, 256, 0, stream>>>(y3, stats + 1024, out_feat);
}

// Round 5
// 1308.580 us; speedup vs baseline: 2.3079x; 1.3231x over previous
//
#include <hip/hip_runtime.h>
#include <cstdint>
#include <cstddef>

#define B   32
#define N   4096
#define NP  512
#define NS  16
#define C   256
#define CIN 259
#define HID 128
#define SB  (NP*NS)      // 8192 columns per batch
#define S   (B*SB)       // 262144 total columns
#define EPSF 1e-5f

#define FPS_BLOCKS 32
#define TR_BLOCKS  (B*256)   // 8192 transpose tiles
#define PREP_BLOCKS 64

// ---------------- fused front: FPS (blocks 0..31) + feat transpose + weight prep ----------------
// FPS blocks: 512 thr, coords in registers, one barrier per step via monotonic-key LDS atomicMax.
// Helper blocks run on the otherwise-idle CUs during the 511-step sequential FPS.
__global__ __launch_bounds__(512) void fused_front_kernel(
        const float* __restrict__ seed, const float* __restrict__ xyz,
        const float* __restrict__ feat, const float* __restrict__ w1,
        const float* __restrict__ w2, const float* __restrict__ w3,
        float* __restrict__ featT, float* __restrict__ w1ft,
        float* __restrict__ w2t, float* __restrict__ w3t, float* __restrict__ stats,
        int* __restrict__ inds, float* __restrict__ out_newxyz,
        float* __restrict__ out_inds_f) {
    __shared__ float smem[3 * N];                 // 48 KB overlay (fps coords / transpose tile)
    __shared__ unsigned long long slot[2];
    int bid = blockIdx.x;
    int t = threadIdx.x;

    if (bid >= FPS_BLOCKS) {
        int hb = bid - FPS_BLOCKS;
        if (hb < TR_BLOCKS) {
            // ---- transpose feat (B,C,N) -> featT (B,N,256), 32x128 tile ----
            float* ls = smem;                      // ls[cc][jj] = smem[cc*129+jj]
            int b = hb >> 8, rem = hb & 255;
            int ct = rem >> 5, jt = rem & 31;
            int c0 = ct * 32, j0 = jt * 128;
            const float* src = feat + (size_t)b * C * N;
            #pragma unroll
            for (int i = 0; i < 8; i++) {
                int lin = t + 512 * i;
                int jj = lin & 127, cc = lin >> 7;
                ls[cc * 129 + jj] = src[(size_t)(c0 + cc) * N + j0 + jj];
            }
            __syncthreads();
            float4* dst = (float4*)featT;
            #pragma unroll
            for (int i = 0; i < 2; i++) {
                int lin = t + 512 * i;
                int cc4 = lin & 7, jj = lin >> 3;
                float4 v = make_float4(ls[(cc4 * 4 + 0) * 129 + jj], ls[(cc4 * 4 + 1) * 129 + jj],
                                       ls[(cc4 * 4 + 2) * 129 + jj], ls[(cc4 * 4 + 3) * 129 + jj]);
                dst[((size_t)b * N + j0 + jj) * 64 + ct * 8 + cc4] = v;
            }
        } else {
            // ---- prep: w1 feat-part k-major, w2/w3 k-major, zero stats ----
            int i = (hb - TR_BLOCKS) * 512 + t;
            if (i < 256 * HID) { int k = i >> 7, o = i & 127; w1ft[i] = w1[o * CIN + 3 + k]; }
            if (i < HID * HID) { int k = i >> 7, o = i & 127; w2t[i] = w2[o * HID + k]; w3t[i] = w3[o * HID + k]; }
            if (i < 3 * 512) stats[i] = 0.f;
        }
        return;
    }

    // ---- FPS for batch b = bid ----
    float* sx = smem;
    float* sy = smem + N;
    float* sz = smem + 2 * N;
    int b = bid;
    const float* sp = seed + (size_t)b * N * 3;
    float px[8], py[8], pz[8], dloc[8];
    #pragma unroll
    for (int u = 0; u < 8; u++) {
        int i = t + 512 * u;
        float x = sp[i * 3 + 0], y = sp[i * 3 + 1], z = sp[i * 3 + 2];
        sx[i] = x; sy[i] = y; sz[i] = z;
        px[u] = x; py[u] = y; pz[u] = z;
        dloc[u] = 1e10f;
    }
    int* binds = inds + b * NP;
    if (t == 0) { slot[0] = 0ull; slot[1] = 0ull; binds[0] = 0; }
    __syncthreads();
    int last = 0;
    int lane = t & 63;
    for (int k = 1; k < NP; k++) {
        float lx = sx[last], ly = sy[last], lz = sz[last];
        float bv = -1.f; int bi = 0x7fffffff;
        #pragma unroll
        for (int u = 0; u < 8; u++) {
            int i = t + 512 * u;
            float dx = __fsub_rn(px[u], lx);
            float dy = __fsub_rn(py[u], ly);
            float dz = __fsub_rn(pz[u], lz);
            float d  = __fadd_rn(__fadd_rn(__fmul_rn(dx, dx), __fmul_rn(dy, dy)), __fmul_rn(dz, dz));
            float dm = fminf(dloc[u], d);
            dloc[u] = dm;
            if (dm > bv || (dm == bv && i < bi)) { bv = dm; bi = i; }
        }
        // monotonic key: larger iter > any older; then larger dist; tie -> smaller index
        unsigned long long key = ((unsigned long long)k << 44)
                               | ((unsigned long long)__float_as_uint(bv) << 12)
                               | (unsigned long long)(4095 - bi);
        #pragma unroll
        for (int off = 32; off > 0; off >>= 1) {
            unsigned long long o = __shfl_down(key, off);
            key = (o > key) ? o : key;
        }
        if (lane == 0) atomicMax(&slot[k & 1], key);
        __syncthreads();
        unsigned long long w = slot[k & 1];        // iter-k keys dominate stale same-parity values
        last = 4095 - (int)(w & 0xFFFull);
        if (t == 0) binds[k] = last;
    }
    __syncthreads();
    for (int p = t; p < NP; p += 512) {
        int j = binds[p];
        const float* xb = xyz + ((size_t)b * N + j) * 3;
        float* ob = out_newxyz + ((size_t)b * NP + p) * 3;
        ob[0] = xb[0]; ob[1] = xb[1]; ob[2] = xb[2];
        out_inds_f[b * NP + p] = (float)j;
    }
}

// ---------------- ball query: wave-parallel ballot scan, first NS by index ----------------
__global__ __launch_bounds__(256) void ballquery_kernel(const float* __restrict__ xyz,
        const float* __restrict__ newxyz, int* __restrict__ idx) {
    __shared__ float sx[N], sy[N], sz[N];
    int blk = blockIdx.x;            // 1024 blocks: 32 per batch, 16 queries each
    int b   = blk >> 5;
    int q00 = (blk & 31) * 16;
    int t = threadIdx.x, lane = t & 63, w = t >> 6;
    const float* xb = xyz + (size_t)b * N * 3;
    for (int i = t; i < N; i += 256) { sx[i] = xb[i * 3]; sy[i] = xb[i * 3 + 1]; sz[i] = xb[i * 3 + 2]; }
    __syncthreads();
    for (int qi = 0; qi < 4; qi++) {
        int q = q00 + w * 4 + qi;
        const float* nq = newxyz + ((size_t)(b * NP + q)) * 3;
        float qx = nq[0], qy = nq[1], qz = nq[2];
        int* out = idx + ((size_t)(b * NP + q)) * NS;
        int cnt = 0, first = -1;
        for (int it = 0; it < 64; it++) {
            int j = it * 64 + lane;
            float dx = __fsub_rn(sx[j], qx);
            float dy = __fsub_rn(sy[j], qy);
            float dz = __fsub_rn(sz[j], qz);
            float d2 = __fadd_rn(__fadd_rn(__fmul_rn(dx, dx), __fmul_rn(dy, dy)), __fmul_rn(dz, dz));
            bool inb = d2 < 0.09f;
            unsigned long long m = __ballot(inb);
            if (m) {
                if (first < 0) first = it * 64 + __builtin_ctzll(m);
                if (inb) {
                    int r = cnt + __popcll(m & ((1ull << lane) - 1ull));
                    if (r < NS) out[r] = j;
                }
                cnt += __popcll(m);
                if (cnt >= NS) break;
            }
        }
        if (cnt < NS && lane >= cnt && lane < NS) out[lane] = first;
    }
}

// ---------------- GEMM1: Y1 = W1feat * gathered featT rows (+xyz in epilogue), + stats ----------------
__global__ __launch_bounds__(256) void gemm1_kernel(const float* __restrict__ w1ft,
        const float* __restrict__ w1raw, const float* __restrict__ featT,
        const float* __restrict__ newxyz, const float* __restrict__ xyz,
        const int* __restrict__ idx, float* __restrict__ yout, float* __restrict__ stats) {
    __shared__ float Ws[32 * 128];
    __shared__ float Xs[32 * 132];
    __shared__ float xn0[128], xn1[128], xn2[128];
    __shared__ int   jl[128];
    __shared__ float bsum[128], bsq[128];
    int t  = threadIdx.x;
    int s0 = blockIdx.x * 128;
    int b  = s0 >> 13;
    if (t < 128) {
        int pn = (s0 & (SB - 1)) + t;
        int p = pn >> 4, n = pn & 15;
        int j = idx[((size_t)(b * NP + p)) * NS + n];
        jl[t] = j;
        const float* xb = xyz + ((size_t)(b * N + j)) * 3;
        const float* nq = newxyz + ((size_t)(b * NP + p)) * 3;
        xn0[t] = (xb[0] - nq[0]) / 0.3f;
        xn1[t] = (xb[1] - nq[1]) / 0.3f;
        xn2[t] = (xb[2] - nq[2]) / 0.3f;
        bsum[t] = 0.f; bsq[t] = 0.f;
    }
    __syncthreads();
    const float4* fT = (const float4*)featT + (size_t)b * N * 64;
    const float4* W4 = (const float4*)w1ft;
    float acc[8][8] = {};
    int tx = t & 15, ty = t >> 4;
    int colA = t >> 3, q = t & 7;
    long rb0 = (long)jl[colA] * 64,      rb1 = (long)jl[colA + 32] * 64;
    long rb2 = (long)jl[colA + 64] * 64, rb3 = (long)jl[colA + 96] * 64;
    for (int kt = 0; kt < 256; kt += 32) {
        int kq = kt >> 2;
        #pragma unroll
        for (int i = 0; i < 4; i++) {
            int lin = t + 256 * i;
            int kk = lin >> 5, of4 = lin & 31;
            *(float4*)&Ws[kk * 128 + of4 * 4] = W4[(size_t)(kt + kk) * 32 + of4];
        }
        float4 x0 = fT[rb0 + kq + q];
        float4 x1 = fT[rb1 + kq + q];
        float4 x2 = fT[rb2 + kq + q];
        float4 x3 = fT[rb3 + kq + q];
        int kr = q * 4;
        Xs[(kr+0)*132 + colA]    = x0.x; Xs[(kr+1)*132 + colA]    = x0.y;
        Xs[(kr+2)*132 + colA]    = x0.z; Xs[(kr+3)*132 + colA]    = x0.w;
        Xs[(kr+0)*132 + colA+32] = x1.x; Xs[(kr+1)*132 + colA+32] = x1.y;
        Xs[(kr+2)*132 + colA+32] = x1.z; Xs[(kr+3)*132 + colA+32] = x1.w;
        Xs[(kr+0)*132 + colA+64] = x2.x; Xs[(kr+1)*132 + colA+64] = x2.y;
        Xs[(kr+2)*132 + colA+64] = x2.z; Xs[(kr+3)*132 + colA+64] = x2.w;
        Xs[(kr+0)*132 + colA+96] = x3.x; Xs[(kr+1)*132 + colA+96] = x3.y;
        Xs[(kr+2)*132 + colA+96] = x3.z; Xs[(kr+3)*132 + colA+96] = x3.w;
        __syncthreads();
        #pragma unroll 4
        for (int kk = 0; kk < 32; kk++) {
            float wv[8], xv[8];
            *(float4*)&wv[0] = *(const float4*)&Ws[kk * 128 + ty * 8];
            *(float4*)&wv[4] = *(const float4*)&Ws[kk * 128 + ty * 8 + 4];
            *(float4*)&xv[0] = *(const float4*)&Xs[kk * 132 + tx * 8];
            *(float4*)&xv[4] = *(const float4*)&Xs[kk * 132 + tx * 8 + 4];
            #pragma unroll
            for (int r = 0; r < 8; r++)
                #pragma unroll
                for (int c = 0; c < 8; c++)
                    acc[r][c] = fmaf(wv[r], xv[c], acc[r][c]);
        }
        __syncthreads();
    }
    float xnc0[8], xnc1[8], xnc2[8];
    #pragma unroll
    for (int c = 0; c < 8; c++) {
        int col = tx * 8 + c;
        xnc0[c] = xn0[col]; xnc1[c] = xn1[col]; xnc2[c] = xn2[col];
    }
    #pragma unroll
    for (int r = 0; r < 8; r++) {
        int o = ty * 8 + r;
        const float* wr = w1raw + (size_t)o * CIN;
        float wa = wr[0], wb = wr[1], wc = wr[2];
        float ls = 0.f, lq = 0.f;
        #pragma unroll
        for (int c = 0; c < 8; c++) {
            float v = acc[r][c] + wa * xnc0[c] + wb * xnc1[c] + wc * xnc2[c];
            ls += v; lq = fmaf(v, v, lq);
            yout[(size_t)o * S + s0 + tx * 8 + c] = v;
        }
        atomicAdd(&bsum[o], ls);
        atomicAdd(&bsq[o], lq);
    }
    __syncthreads();
    if (t < 128) {
        atomicAdd(&stats[t], bsum[t]);
        atomicAdd(&stats[128 + t], bsq[t]);
    }
}

// ---------------- GEMM2/3: X = relu(affine(Yprev)), Y = W*X, + stats ----------------
__global__ __launch_bounds__(256) void gemm_bn_kernel(const float* __restrict__ wt,
        const float* __restrict__ yprev, const float* __restrict__ statsPrev,
        float* __restrict__ yout, float* __restrict__ statsOut) {
    __shared__ float Ws[32 * 128];
    __shared__ float Xs[32 * 132];
    __shared__ float ssc[128], ssh[128];
    __shared__ float bsum[128], bsq[128];
    int t  = threadIdx.x;
    int s0 = blockIdx.x * 128;
    if (t < 128) {
        ssc[t] = statsPrev[256 + t];
        ssh[t] = statsPrev[384 + t];
        bsum[t] = 0.f; bsq[t] = 0.f;
    }
    __syncthreads();
    const float4* W4 = (const float4*)wt;
    float acc[8][8] = {};
    int tx = t & 15, ty = t >> 4;
    for (int kt = 0; kt < HID; kt += 32) {
        #pragma unroll
        for (int i = 0; i < 4; i++) {
            int lin = t + 256 * i;
            int kk = lin >> 5, of4 = lin & 31;
            *(float4*)&Ws[kk * 128 + of4 * 4] = W4[(size_t)(kt + kk) * 32 + of4];
        }
        #pragma unroll
        for (int i = 0; i < 4; i++) {
            int lin = t + 256 * i;
            int kk = lin >> 5, sc4 = lin & 31;
            int k = kt + kk;
            float4 v = *(const float4*)&yprev[(size_t)k * S + s0 + sc4 * 4];
            float sck = ssc[k], shk = ssh[k];
            v.x = fmaxf(0.f, fmaf(v.x, sck, shk));
            v.y = fmaxf(0.f, fmaf(v.y, sck, shk));
            v.z = fmaxf(0.f, fmaf(v.z, sck, shk));
            v.w = fmaxf(0.f, fmaf(v.w, sck, shk));
            *(float4*)&Xs[kk * 132 + sc4 * 4] = v;
        }
        __syncthreads();
        #pragma unroll 4
        for (int kk = 0; kk < 32; kk++) {
            float wv[8], xv[8];
            *(float4*)&wv[0] = *(const float4*)&Ws[kk * 128 + ty * 8];
            *(float4*)&wv[4] = *(const float4*)&Ws[kk * 128 + ty * 8 + 4];
            *(float4*)&xv[0] = *(const float4*)&Xs[kk * 132 + tx * 8];
            *(float4*)&xv[4] = *(const float4*)&Xs[kk * 132 + tx * 8 + 4];
            #pragma unroll
            for (int r = 0; r < 8; r++)
                #pragma unroll
                for (int c = 0; c < 8; c++)
                    acc[r][c] = fmaf(wv[r], xv[c], acc[r][c]);
        }
        __syncthreads();
    }
    #pragma unroll
    for (int r = 0; r < 8; r++) {
        int o = ty * 8 + r;
        float ls = 0.f, lq = 0.f;
        #pragma unroll
        for (int c = 0; c < 8; c++) {
            float v = acc[r][c];
            ls += v; lq = fmaf(v, v, lq);
            yout[(size_t)o * S + s0 + tx * 8 + c] = v;
        }
        atomicAdd(&bsum[o], ls);
        atomicAdd(&bsq[o], lq);
    }
    __syncthreads();
    if (t < 128) {
        atomicAdd(&statsOut[t], bsum[t]);
        atomicAdd(&statsOut[128 + t], bsq[t]);
    }
}

// ---------------- BN params ----------------
__global__ void bnparam_kernel(float* __restrict__ stats, const float* __restrict__ g,
                               const float* __restrict__ be) {
    int o = threadIdx.x;
    float mean = stats[o] * (1.f / (float)S);
    float var  = stats[128 + o] * (1.f / (float)S) - mean * mean;
    float sc = g[o] / sqrtf(var + EPSF);
    stats[256 + o] = sc;
    stats[384 + o] = be[o] - mean * sc;
}

// ---------------- final: affine+relu+max over NS ----------------
__global__ __launch_bounds__(256) void maxpool_kernel(const float* __restrict__ y3,
        const float* __restrict__ stats3, float* __restrict__ out1) {
    int i = blockIdx.x * 256 + threadIdx.x;
    if (i >= B * HID * NP) return;
    int p = i % NP;
    int o = (i / NP) % HID;
    int b = i / (NP * HID);
    float sc = stats3[256 + o], sh = stats3[384 + o];
    const float4* y4 = (const float4*)(y3 + (size_t)o * S + (size_t)(b * NP + p) * NS);
    float m = 0.f;
    #pragma unroll
    for (int n4 = 0; n4 < 4; n4++) {
        float4 v = y4[n4];
        m = fmaxf(m, fmaf(v.x, sc, sh));
        m = fmaxf(m, fmaf(v.y, sc, sh));
        m = fmaxf(m, fmaf(v.z, sc, sh));
        m = fmaxf(m, fmaf(v.w, sc, sh));
    }
    out1[i] = m;
}

extern "C" void kernel_launch(void* const* d_in, const int* in_sizes, int n_in,
                              void* d_out, int out_size, void* d_ws, size_t ws_size,
                              hipStream_t stream) {
    const float* xyz  = (const float*)d_in[0];
    const float* feat = (const float*)d_in[1];
    const float* seed = (const float*)d_in[2];
    const float* w1 = (const float*)d_in[3];
    const float* g1 = (const float*)d_in[4];
    const float* be1 = (const float*)d_in[5];
    const float* w2 = (const float*)d_in[6];
    const float* g2 = (const float*)d_in[7];
    const float* be2 = (const float*)d_in[8];
    const float* w3 = (const float*)d_in[9];
    const float* g3 = (const float*)d_in[10];
    const float* be3 = (const float*)d_in[11];

    float* out_newxyz = (float*)d_out;                 // (B,NP,3)
    float* out_feat   = out_newxyz + B * NP * 3;       // (B,HID,NP)
    float* out_inds   = out_feat + B * HID * NP;       // (B,NP) as float

    float* stats = (float*)d_ws;                       // 3 x [sum|sq|scale|shift] x 128
    int*   inds  = (int*)(stats + 3 * 512);            // B*NP
    int*   idx   = inds + B * NP;                      // B*NP*NS
    float* w1ft  = (float*)(idx + (size_t)B * NP * NS);
    float* w2t   = w1ft + 256 * HID;
    float* w3t   = w2t + HID * HID;
    float* featT = w3t + HID * HID;                    // B*N*256
    float* y1    = featT + (size_t)B * N * 256;        // HID*S
    float* y2    = featT;                              // alias: featT dead after gemm1
    float* y3    = y1;                                 // alias: y1 dead after gemm2

    size_t need = ((size_t)(3 * 512 + B * NP + (size_t)B * NP * NS
                   + 256 * HID + 2 * HID * HID)
                   + (size_t)B * N * 256 + (size_t)HID * S) * 4;

    if (ws_size < need) return;

    fused_front_kernel<<<FPS_BLOCKS + TR_BLOCKS + PREP_BLOCKS, 512, 0, stream>>>(
        seed, xyz, feat, w1, w2, w3, featT, w1ft, w2t, w3t, stats,
        inds, out_newxyz, out_inds);
    ballquery_kernel<<<B * 32, 256, 0, stream>>>(xyz, out_newxyz, idx);
    gemm1_kernel<<<S / 128, 256, 0, stream>>>(w1ft, w1, featT, out_newxyz, xyz, idx, y1, stats);
    bnparam_kernel<<<1, HID, 0, stream>>>(stats, g1, be1);
    gemm_bn_kernel<<<S / 128, 256, 0, stream>>>(w2t, y1, stats, y2, stats + 512);
    bnparam_kernel<<<1, HID, 0, stream>>>(stats + 512, g2, be2);
    gemm_bn_kernel<<<S / 128, 256, 0, stream>>>(w3t, y2, stats + 512, y3, stats + 1024);
    bnparam_kernel<<<1, HID, 0, stream>>>(stats + 1024, g3, be3);
    maxpool_kernel<<<(B * HID * NP + 255) / 256, 256, 0, stream>>>(y3, stats + 1024, out_feat);
}

// Round 6
// 907.112 us; speedup vs baseline: 3.3293x; 1.4426x over previous
//
#include <hip/hip_runtime.h>
#include <cstdint>
#include <cstddef>

#define B   32
#define N   4096
#define NP  512
#define NS  16
#define C   256
#define CIN 259
#define HID 128
#define SB  (NP*NS)      // 8192 columns per batch
#define S   (B*SB)       // 262144 total columns
#define EPSF 1e-5f

#define FPS_BLOCKS 32
#define TR_BLOCKS  (B*256)   // 8192 transpose tiles
#define PREP_BLOCKS 64

typedef __attribute__((ext_vector_type(8))) short short8;
typedef __attribute__((ext_vector_type(4))) float floatx4;

__device__ __forceinline__ float bf2f(unsigned short u) {
    return __uint_as_float(((unsigned)u) << 16);
}
__device__ __forceinline__ unsigned short f2bf(float f) {
    unsigned u = __float_as_uint(f);
    return (unsigned short)((u + 0x7FFFu + ((u >> 16) & 1u)) >> 16);
}

// wave64 max of nonneg-float bits via DPP (VALU pipe, no LDS crossbar), result uniform
__device__ __forceinline__ int wave_max_i32(int x) {
    int y;
    y = __builtin_amdgcn_update_dpp(0, x, 0x111, 0xf, 0xf, true); x = (y > x) ? y : x;
    y = __builtin_amdgcn_update_dpp(0, x, 0x112, 0xf, 0xf, true); x = (y > x) ? y : x;
    y = __builtin_amdgcn_update_dpp(0, x, 0x114, 0xf, 0xf, true); x = (y > x) ? y : x;
    y = __builtin_amdgcn_update_dpp(0, x, 0x118, 0xf, 0xf, true); x = (y > x) ? y : x;
    y = __builtin_amdgcn_update_dpp(0, x, 0x142, 0xa, 0xf, true); x = (y > x) ? y : x;
    y = __builtin_amdgcn_update_dpp(0, x, 0x143, 0xc, 0xf, true); x = (y > x) ? y : x;
    return __builtin_amdgcn_readlane(x, 63);
}
__device__ __forceinline__ unsigned wave_max_u32(unsigned x) {
    unsigned y;
    y = (unsigned)__builtin_amdgcn_update_dpp(0, (int)x, 0x111, 0xf, 0xf, true); x = (y > x) ? y : x;
    y = (unsigned)__builtin_amdgcn_update_dpp(0, (int)x, 0x112, 0xf, 0xf, true); x = (y > x) ? y : x;
    y = (unsigned)__builtin_amdgcn_update_dpp(0, (int)x, 0x114, 0xf, 0xf, true); x = (y > x) ? y : x;
    y = (unsigned)__builtin_amdgcn_update_dpp(0, (int)x, 0x118, 0xf, 0xf, true); x = (y > x) ? y : x;
    y = (unsigned)__builtin_amdgcn_update_dpp(0, (int)x, 0x142, 0xa, 0xf, true); x = (y > x) ? y : x;
    y = (unsigned)__builtin_amdgcn_update_dpp(0, (int)x, 0x143, 0xc, 0xf, true); x = (y > x) ? y : x;
    return (unsigned)__builtin_amdgcn_readlane((int)x, 63);
}

// ---------------- fused front: FPS + feat transpose(bf16) + weight prep(bf16) ----------------
__global__ __launch_bounds__(512) void fused_front_kernel(
        const float* __restrict__ seed, const float* __restrict__ xyz,
        const float* __restrict__ feat, const float* __restrict__ w1,
        const float* __restrict__ w2, const float* __restrict__ w3,
        unsigned short* __restrict__ featT, unsigned short* __restrict__ w1fb,
        unsigned short* __restrict__ w2b, unsigned short* __restrict__ w3b,
        float* __restrict__ stats, int* __restrict__ inds,
        float* __restrict__ out_newxyz, float* __restrict__ out_inds_f) {
    __shared__ float smem[3 * N];                 // 48 KB overlay
    __shared__ unsigned long long slot8[16];      // [parity][wave]
    int bid = blockIdx.x;
    int t = threadIdx.x;

    if (bid >= FPS_BLOCKS) {
        int hb = bid - FPS_BLOCKS;
        if (hb < TR_BLOCKS) {
            // ---- transpose feat (B,C,N) fp32 -> featT (B,N,256) bf16, 32x128 tile ----
            float* ls = smem;
            int b2 = hb >> 8, rem = hb & 255;
            int ct = rem >> 5, jt = rem & 31;
            int c0 = ct * 32, j0 = jt * 128;
            const float* src = feat + (size_t)b2 * C * N;
            #pragma unroll
            for (int i = 0; i < 8; i++) {
                int lin = t + 512 * i;
                int jj = lin & 127, cc = lin >> 7;
                ls[cc * 129 + jj] = src[(size_t)(c0 + cc) * N + j0 + jj];
            }
            __syncthreads();
            int c8 = t & 3, jj = t >> 2;
            unsigned pk[4];
            #pragma unroll
            for (int q = 0; q < 4; q++) {
                float f0 = ls[(c8 * 8 + 2 * q) * 129 + jj];
                float f1 = ls[(c8 * 8 + 2 * q + 1) * 129 + jj];
                pk[q] = (unsigned)f2bf(f0) | ((unsigned)f2bf(f1) << 16);
            }
            *(uint4*)&featT[((size_t)b2 * N + j0 + jj) * 256 + c0 + c8 * 8] =
                make_uint4(pk[0], pk[1], pk[2], pk[3]);
        } else {
            // ---- prep: weights -> bf16 [o][k]; zero stats ----
            int i0 = (hb - TR_BLOCKS) * 512 + t;
            if (i0 < 256 * HID) { int o = i0 >> 8, k = i0 & 255; w1fb[i0] = f2bf(w1[o * CIN + 3 + k]); }
            if (i0 < HID * HID) { w2b[i0] = f2bf(w2[i0]); w3b[i0] = f2bf(w3[i0]); }
            if (i0 < 3 * 512) stats[i0] = 0.f;
        }
        return;
    }

    // ---- FPS for batch b = bid ----
    float* sx = smem;
    float* sy = smem + N;
    float* sz = smem + 2 * N;
    int b = bid;
    const float* sp = seed + (size_t)b * N * 3;
    float px[8], py[8], pz[8], dloc[8];
    #pragma unroll
    for (int u = 0; u < 8; u++) {
        int i = t + 512 * u;
        float x = sp[i * 3 + 0], y = sp[i * 3 + 1], z = sp[i * 3 + 2];
        sx[i] = x; sy[i] = y; sz[i] = z;
        px[u] = x; py[u] = y; pz[u] = z;
        dloc[u] = 1e10f;
    }
    int* binds = inds + b * NP;
    if (t == 0) binds[0] = 0;
    if (t < 16) slot8[t] = 0ull;
    __syncthreads();
    int last = 0;
    int lane = t & 63, w = t >> 6;
    for (int k = 1; k < NP; k++) {
        float lx = sx[last], ly = sy[last], lz = sz[last];
        float bv = -1.f; int bi = 0x7fffffff;
        #pragma unroll
        for (int u = 0; u < 8; u++) {
            int i = t + 512 * u;
            float dx = __fsub_rn(px[u], lx);
            float dy = __fsub_rn(py[u], ly);
            float dz = __fsub_rn(pz[u], lz);
            float d  = __fadd_rn(__fadd_rn(__fmul_rn(dx, dx), __fmul_rn(dy, dy)), __fmul_rn(dz, dz));
            float dm = fminf(dloc[u], d);
            dloc[u] = dm;
            if (dm > bv || (dm == bv && i < bi)) { bv = dm; bi = i; }
        }
        // phase 1: wave max distance (nonneg f32 -> int compare valid), DPP
        int wm = wave_max_i32(__float_as_int(bv));
        // phase 2: min index among lanes holding the max (unsigned max of ~idx; OOB 0 loses)
        unsigned cand = (__float_as_int(bv) == wm) ? ~(unsigned)bi : 0u;
        unsigned win = wave_max_u32(cand);
        int wbi = (int)(~win);
        if (lane == 0)
            slot8[(k & 1) * 8 + w] =
                (((unsigned long long)(unsigned)wm) << 12) | (unsigned)(4095 - wbi);
        __syncthreads();
        unsigned long long best = slot8[(k & 1) * 8];
        #pragma unroll
        for (int j = 1; j < 8; j++) {
            unsigned long long v = slot8[(k & 1) * 8 + j];
            if (v > best) best = v;
        }
        last = 4095 - (int)(best & 0xFFFull);
        if (t == 0) binds[k] = last;
    }
    __syncthreads();
    {
        int p = t;   // 512 threads cover NP=512
        int j = binds[p];
        const float* xb = xyz + ((size_t)b * N + j) * 3;
        float* ob = out_newxyz + ((size_t)b * NP + p) * 3;
        ob[0] = xb[0]; ob[1] = xb[1]; ob[2] = xb[2];
        out_inds_f[b * NP + p] = (float)j;
    }
}

// ---------------- ball query: wave-parallel ballot scan, first NS by index ----------------
__global__ __launch_bounds__(256) void ballquery_kernel(const float* __restrict__ xyz,
        const float* __restrict__ newxyz, int* __restrict__ idx) {
    __shared__ float sx[N], sy[N], sz[N];
    int blk = blockIdx.x;
    int b   = blk >> 5;
    int q00 = (blk & 31) * 16;
    int t = threadIdx.x, lane = t & 63, w = t >> 6;
    const float* xb = xyz + (size_t)b * N * 3;
    for (int i = t; i < N; i += 256) { sx[i] = xb[i * 3]; sy[i] = xb[i * 3 + 1]; sz[i] = xb[i * 3 + 2]; }
    __syncthreads();
    for (int qi = 0; qi < 4; qi++) {
        int q = q00 + w * 4 + qi;
        const float* nq = newxyz + ((size_t)(b * NP + q)) * 3;
        float qx = nq[0], qy = nq[1], qz = nq[2];
        int* out = idx + ((size_t)(b * NP + q)) * NS;
        int cnt = 0, first = -1;
        for (int it = 0; it < 64; it++) {
            int j = it * 64 + lane;
            float dx = __fsub_rn(sx[j], qx);
            float dy = __fsub_rn(sy[j], qy);
            float dz = __fsub_rn(sz[j], qz);
            float d2 = __fadd_rn(__fadd_rn(__fmul_rn(dx, dx), __fmul_rn(dy, dy)), __fmul_rn(dz, dz));
            bool inb = d2 < 0.09f;
            unsigned long long m = __ballot(inb);
            if (m) {
                if (first < 0) first = it * 64 + __builtin_ctzll(m);
                if (inb) {
                    int r = cnt + __popcll(m & ((1ull << lane) - 1ull));
                    if (r < NS) out[r] = j;
                }
                cnt += __popcll(m);
                if (cnt >= NS) break;
            }
        }
        if (cnt < NS && lane >= cnt && lane < NS) out[lane] = first;
    }
}

// ---------------- GEMM1 (MFMA bf16): y1[s][o] = w1feat . gathered featT + xyz epilogue ----------------
__global__ __launch_bounds__(256) void gemm1_mfma(
        const unsigned short* __restrict__ w1fb, const float* __restrict__ w1raw,
        const unsigned short* __restrict__ featT, const float* __restrict__ newxyz,
        const float* __restrict__ xyz, const int* __restrict__ idx,
        unsigned short* __restrict__ y1) {
    __shared__ unsigned short Xs[128][136];       // [s][k] slab, reused as [s][o] out tile
    __shared__ float xn0[128], xn1[128], xn2[128];
    __shared__ int jl[128];
    int t = threadIdx.x;
    int s0 = blockIdx.x * 128;
    int b = s0 >> 13;
    if (t < 128) {
        int pn = (s0 & (SB - 1)) + t;
        int p = pn >> 4, n = pn & 15;
        int j = idx[((size_t)(b * NP + p)) * NS + n];
        jl[t] = j;
        const float* xb = xyz + ((size_t)(b * N + j)) * 3;
        const float* nq = newxyz + ((size_t)(b * NP + p)) * 3;
        xn0[t] = (xb[0] - nq[0]) / 0.3f;
        xn1[t] = (xb[1] - nq[1]) / 0.3f;
        xn2[t] = (xb[2] - nq[2]) / 0.3f;
    }
    __syncthreads();
    int lane = t & 63, w = t >> 6;
    int row16 = lane & 15, quad = lane >> 4;
    floatx4 acc[2][8];
    #pragma unroll
    for (int mt = 0; mt < 2; mt++)
        #pragma unroll
        for (int nt = 0; nt < 8; nt++)
            acc[mt][nt] = (floatx4){0.f, 0.f, 0.f, 0.f};
    int ss = t >> 1, hh = (t & 1) * 64;
    const unsigned short* grow = featT + ((size_t)b * N + jl[ss]) * 256 + hh;
    for (int slab = 0; slab < 2; slab++) {
        int k0 = slab * 128;
        {
            const uint4* src = (const uint4*)(grow + k0);
            #pragma unroll
            for (int i = 0; i < 8; i++)
                *(uint4*)&Xs[ss][hh + i * 8] = src[i];
        }
        __syncthreads();
        #pragma unroll
        for (int kk = 0; kk < 128; kk += 32) {
            short8 a0 = *(const short8*)&w1fb[(size_t)(w * 32 + row16) * 256 + k0 + kk + quad * 8];
            short8 a1 = *(const short8*)&w1fb[(size_t)(w * 32 + 16 + row16) * 256 + k0 + kk + quad * 8];
            #pragma unroll
            for (int nt = 0; nt < 8; nt++) {
                short8 bf = *(const short8*)&Xs[nt * 16 + row16][kk + quad * 8];
                acc[0][nt] = __builtin_amdgcn_mfma_f32_16x16x32_bf16(a0, bf, acc[0][nt], 0, 0, 0);
                acc[1][nt] = __builtin_amdgcn_mfma_f32_16x16x32_bf16(a1, bf, acc[1][nt], 0, 0, 0);
            }
        }
        __syncthreads();
    }
    // epilogue: + w1_xyz . xn (fp32), pack bf16, tile [s][o], coalesced global write
    float wa[8], wbv[8], wc[8];
    #pragma unroll
    for (int mt = 0; mt < 2; mt++)
        #pragma unroll
        for (int r = 0; r < 4; r++) {
            int o = w * 32 + mt * 16 + quad * 4 + r;
            const float* wr = w1raw + (size_t)o * CIN;
            wa[mt * 4 + r] = wr[0]; wbv[mt * 4 + r] = wr[1]; wc[mt * 4 + r] = wr[2];
        }
    float x0l[8], x1l[8], x2l[8];
    #pragma unroll
    for (int nt = 0; nt < 8; nt++) {
        int s = nt * 16 + row16;
        x0l[nt] = xn0[s]; x1l[nt] = xn1[s]; x2l[nt] = xn2[s];
    }
    #pragma unroll
    for (int mt = 0; mt < 2; mt++)
        #pragma unroll
        for (int nt = 0; nt < 8; nt++) {
            int s = nt * 16 + row16;
            int ob = w * 32 + mt * 16 + quad * 4;
            floatx4 a = acc[mt][nt];
            float v0 = a[0] + wa[mt*4+0]*x0l[nt] + wbv[mt*4+0]*x1l[nt] + wc[mt*4+0]*x2l[nt];
            float v1 = a[1] + wa[mt*4+1]*x0l[nt] + wbv[mt*4+1]*x1l[nt] + wc[mt*4+1]*x2l[nt];
            float v2 = a[2] + wa[mt*4+2]*x0l[nt] + wbv[mt*4+2]*x1l[nt] + wc[mt*4+2]*x2l[nt];
            float v3 = a[3] + wa[mt*4+3]*x0l[nt] + wbv[mt*4+3]*x1l[nt] + wc[mt*4+3]*x2l[nt];
            unsigned p0 = (unsigned)f2bf(v0) | ((unsigned)f2bf(v1) << 16);
            unsigned p1 = (unsigned)f2bf(v2) | ((unsigned)f2bf(v3) << 16);
            *(uint2*)&Xs[s][ob] = make_uint2(p0, p1);
        }
    __syncthreads();
    int c = t & 15, sr = t >> 4;
    #pragma unroll
    for (int i = 0; i < 8; i++) {
        int s = sr + 16 * i;
        uint4 v = *(const uint4*)&Xs[s][c * 8];
        *(uint4*)&y1[(size_t)(s0 + s) * 128 + c * 8] = v;
    }
}

// ---------------- GEMM2/3 (MFMA bf16): X = relu(affine(yprev)), Y[s][o] = W*X ----------------
__global__ __launch_bounds__(256) void gemm_bn_mfma(
        const unsigned short* __restrict__ wb16, const unsigned short* __restrict__ yprev,
        const float* __restrict__ statsPrev, unsigned short* __restrict__ yout) {
    __shared__ unsigned short Xs[128][136];
    __shared__ float ssc[128], ssh[128];
    int t = threadIdx.x;
    int s0 = blockIdx.x * 128;
    if (t < 128) { ssc[t] = statsPrev[256 + t]; ssh[t] = statsPrev[384 + t]; }
    __syncthreads();
    int ss = t >> 1, hh = (t & 1) * 64;
    {
        const uint4* src = (const uint4*)&yprev[(size_t)(s0 + ss) * 128 + hh];
        #pragma unroll
        for (int i = 0; i < 8; i++) {
            uint4 raw = src[i];
            int kb = hh + i * 8;
            float4 c0 = *(float4*)&ssc[kb];
            float4 c1 = *(float4*)&ssc[kb + 4];
            float4 h0 = *(float4*)&ssh[kb];
            float4 h1 = *(float4*)&ssh[kb + 4];
            float f0 = fmaxf(0.f, fmaf(bf2f((unsigned short)(raw.x & 0xFFFF)), c0.x, h0.x));
            float f1 = fmaxf(0.f, fmaf(bf2f((unsigned short)(raw.x >> 16)),    c0.y, h0.y));
            float f2 = fmaxf(0.f, fmaf(bf2f((unsigned short)(raw.y & 0xFFFF)), c0.z, h0.z));
            float f3 = fmaxf(0.f, fmaf(bf2f((unsigned short)(raw.y >> 16)),    c0.w, h0.w));
            float f4 = fmaxf(0.f, fmaf(bf2f((unsigned short)(raw.z & 0xFFFF)), c1.x, h1.x));
            float f5 = fmaxf(0.f, fmaf(bf2f((unsigned short)(raw.z >> 16)),    c1.y, h1.y));
            float f6 = fmaxf(0.f, fmaf(bf2f((unsigned short)(raw.w & 0xFFFF)), c1.z, h1.z));
            float f7 = fmaxf(0.f, fmaf(bf2f((unsigned short)(raw.w >> 16)),    c1.w, h1.w));
            unsigned o0 = (unsigned)f2bf(f0) | ((unsigned)f2bf(f1) << 16);
            unsigned o1 = (unsigned)f2bf(f2) | ((unsigned)f2bf(f3) << 16);
            unsigned o2 = (unsigned)f2bf(f4) | ((unsigned)f2bf(f5) << 16);
            unsigned o3 = (unsigned)f2bf(f6) | ((unsigned)f2bf(f7) << 16);
            *(uint4*)&Xs[ss][kb] = make_uint4(o0, o1, o2, o3);
        }
    }
    __syncthreads();
    int lane = t & 63, w = t >> 6;
    int row16 = lane & 15, quad = lane >> 4;
    floatx4 acc[2][8];
    #pragma unroll
    for (int mt = 0; mt < 2; mt++)
        #pragma unroll
        for (int nt = 0; nt < 8; nt++)
            acc[mt][nt] = (floatx4){0.f, 0.f, 0.f, 0.f};
    #pragma unroll
    for (int kk = 0; kk < 128; kk += 32) {
        short8 a0 = *(const short8*)&wb16[(size_t)(w * 32 + row16) * 128 + kk + quad * 8];
        short8 a1 = *(const short8*)&wb16[(size_t)(w * 32 + 16 + row16) * 128 + kk + quad * 8];
        #pragma unroll
        for (int nt = 0; nt < 8; nt++) {
            short8 bf = *(const short8*)&Xs[nt * 16 + row16][kk + quad * 8];
            acc[0][nt] = __builtin_amdgcn_mfma_f32_16x16x32_bf16(a0, bf, acc[0][nt], 0, 0, 0);
            acc[1][nt] = __builtin_amdgcn_mfma_f32_16x16x32_bf16(a1, bf, acc[1][nt], 0, 0, 0);
        }
    }
    __syncthreads();
    #pragma unroll
    for (int mt = 0; mt < 2; mt++)
        #pragma unroll
        for (int nt = 0; nt < 8; nt++) {
            int s = nt * 16 + row16;
            int ob = w * 32 + mt * 16 + quad * 4;
            floatx4 a = acc[mt][nt];
            unsigned p0 = (unsigned)f2bf(a[0]) | ((unsigned)f2bf(a[1]) << 16);
            unsigned p1 = (unsigned)f2bf(a[2]) | ((unsigned)f2bf(a[3]) << 16);
            *(uint2*)&Xs[s][ob] = make_uint2(p0, p1);
        }
    __syncthreads();
    int c = t & 15, sr = t >> 4;
    #pragma unroll
    for (int i = 0; i < 8; i++) {
        int s = sr + 16 * i;
        uint4 v = *(const uint4*)&Xs[s][c * 8];
        *(uint4*)&yout[(size_t)(s0 + s) * 128 + c * 8] = v;
    }
}

// ---------------- per-channel sum/sumsq over y[s][o] bf16 ----------------
__global__ __launch_bounds__(256) void stats_kernel(const unsigned short* __restrict__ y,
                                                    float* __restrict__ st) {
    __shared__ float ls[128], lq[128];
    int t = threadIdx.x;
    if (t < 128) { ls[t] = 0.f; lq[t] = 0.f; }
    __syncthreads();
    int c = t & 15, r0 = t >> 4;
    float s8[8] = {}, q8[8] = {};
    size_t base0 = (size_t)blockIdx.x * 512;
    for (int i = 0; i < 32; i++) {
        size_t s = base0 + r0 + (size_t)i * 16;
        uint4 v = *(const uint4*)&y[s * 128 + c * 8];
        unsigned ww[4] = {v.x, v.y, v.z, v.w};
        #pragma unroll
        for (int j = 0; j < 4; j++) {
            float f0 = bf2f((unsigned short)(ww[j] & 0xFFFF));
            float f1 = bf2f((unsigned short)(ww[j] >> 16));
            s8[2*j]   += f0; q8[2*j]   = fmaf(f0, f0, q8[2*j]);
            s8[2*j+1] += f1; q8[2*j+1] = fmaf(f1, f1, q8[2*j+1]);
        }
    }
    #pragma unroll
    for (int j = 0; j < 8; j++) {
        atomicAdd(&ls[c * 8 + j], s8[j]);
        atomicAdd(&lq[c * 8 + j], q8[j]);
    }
    __syncthreads();
    if (t < 128) { atomicAdd(&st[t], ls[t]); atomicAdd(&st[128 + t], lq[t]); }
}

// ---------------- BN params ----------------
__global__ void bnparam_kernel(float* __restrict__ stats, const float* __restrict__ g,
                               const float* __restrict__ be) {
    int o = threadIdx.x;
    float mean = stats[o] * (1.f / (float)S);
    float var  = stats[128 + o] * (1.f / (float)S) - mean * mean;
    float sc = g[o] / sqrtf(var + EPSF);
    stats[256 + o] = sc;
    stats[384 + o] = be[o] - mean * sc;
}

// ---------------- final: affine+relu+max over NS (y3 bf16 [s][o]) ----------------
__global__ __launch_bounds__(256) void maxpool_kernel(const unsigned short* __restrict__ y3,
        const float* __restrict__ st, float* __restrict__ out1) {
    int g = blockIdx.x * 256 + threadIdx.x;   // (b, oc, p), p fastest
    int p = g & 511;
    int oc = (g >> 9) & 15;
    int b = g >> 13;
    float sc[8], sh[8];
    #pragma unroll
    for (int j = 0; j < 8; j++) { sc[j] = st[256 + oc * 8 + j]; sh[j] = st[384 + oc * 8 + j]; }
    float m[8];
    #pragma unroll
    for (int j = 0; j < 8; j++) m[j] = 0.f;   // relu floor
    size_t base = ((size_t)(b * NP + p) * NS) * 128 + oc * 8;
    #pragma unroll
    for (int n = 0; n < 16; n++) {
        uint4 v = *(const uint4*)&y3[base + (size_t)n * 128];
        unsigned ww[4] = {v.x, v.y, v.z, v.w};
        #pragma unroll
        for (int j = 0; j < 4; j++) {
            m[2*j]   = fmaxf(m[2*j],   fmaf(bf2f((unsigned short)(ww[j] & 0xFFFF)), sc[2*j],   sh[2*j]));
            m[2*j+1] = fmaxf(m[2*j+1], fmaf(bf2f((unsigned short)(ww[j] >> 16)),    sc[2*j+1], sh[2*j+1]));
        }
    }
    #pragma unroll
    for (int j = 0; j < 8; j++)
        out1[((size_t)b * HID + oc * 8 + j) * NP + p] = m[j];
}

extern "C" void kernel_launch(void* const* d_in, const int* in_sizes, int n_in,
                              void* d_out, int out_size, void* d_ws, size_t ws_size,
                              hipStream_t stream) {
    const float* xyz  = (const float*)d_in[0];
    const float* feat = (const float*)d_in[1];
    const float* seed = (const float*)d_in[2];
    const float* w1 = (const float*)d_in[3];
    const float* g1 = (const float*)d_in[4];
    const float* be1 = (const float*)d_in[5];
    const float* w2 = (const float*)d_in[6];
    const float* g2 = (const float*)d_in[7];
    const float* be2 = (const float*)d_in[8];
    const float* w3 = (const float*)d_in[9];
    const float* g3 = (const float*)d_in[10];
    const float* be3 = (const float*)d_in[11];

    float* out_newxyz = (float*)d_out;                 // (B,NP,3)
    float* out_feat   = out_newxyz + B * NP * 3;       // (B,HID,NP)
    float* out_inds   = out_feat + B * HID * NP;       // (B,NP) as float

    float* stats = (float*)d_ws;                       // 3 x [sum|sq|sc|sh] x 128
    int*   inds  = (int*)(stats + 3 * 512);
    int*   idx   = inds + B * NP;
    unsigned short* w1fb  = (unsigned short*)(idx + (size_t)B * NP * NS);
    unsigned short* w2b   = w1fb + 256 * HID;
    unsigned short* w3b   = w2b + HID * HID;
    unsigned short* featT = w3b + HID * HID;           // B*N*256 bf16
    unsigned short* y1    = featT + (size_t)B * N * 256;   // S*128 bf16
    unsigned short* y2    = featT;                     // alias: featT dead after gemm1
    unsigned short* y3    = y1;                        // alias: y1 dead after gemm2

    size_t need = (size_t)(3 * 512) * 4 + (size_t)B * NP * 4 + (size_t)B * NP * NS * 4
                + (size_t)(256 * HID + 2 * HID * HID) * 2
                + 2ull * (size_t)B * N * 256 * 2;
    if (ws_size < need) return;

    fused_front_kernel<<<FPS_BLOCKS + TR_BLOCKS + PREP_BLOCKS, 512, 0, stream>>>(
        seed, xyz, feat, w1, w2, w3, featT, w1fb, w2b, w3b, stats,
        inds, out_newxyz, out_inds);
    ballquery_kernel<<<B * 32, 256, 0, stream>>>(xyz, out_newxyz, idx);
    gemm1_mfma<<<S / 128, 256, 0, stream>>>(w1fb, w1, featT, out_newxyz, xyz, idx, y1);
    stats_kernel<<<512, 256, 0, stream>>>(y1, stats);
    bnparam_kernel<<<1, HID, 0, stream>>>(stats, g1, be1);
    gemm_bn_mfma<<<S / 128, 256, 0, stream>>>(w2b, y1, stats, y2);
    stats_kernel<<<512, 256, 0, stream>>>(y2, stats + 512);
    bnparam_kernel<<<1, HID, 0, stream>>>(stats + 512, g2, be2);
    gemm_bn_mfma<<<S / 128, 256, 0, stream>>>(w3b, y2, stats + 512, y3);
    stats_kernel<<<512, 256, 0, stream>>>(y3, stats + 1024);
    bnparam_kernel<<<1, HID, 0, stream>>>(stats + 1024, g3, be3);
    maxpool_kernel<<<(B * 16 * NP) / 256, 256, 0, stream>>>(y3, stats + 1024, out_feat);
}